// Round 7
// baseline (1346.211 us; speedup 1.0000x reference)
//
#include <hip/hip_runtime.h>
#include <math.h>

#define TB   720
#define NI   16
#define NH   128
#define NG   512
#define PRED 96

typedef _Float16 h2 __attribute__((ext_vector_type(2)));

__device__ __forceinline__ float sigf(float v) { return 1.0f / (1.0f + __expf(-v)); }

__device__ __forceinline__ float fdot2f(unsigned int a, unsigned int b, float c) {
#if __has_builtin(__builtin_amdgcn_fdot2)
    return __builtin_amdgcn_fdot2(__builtin_bit_cast(h2, a), __builtin_bit_cast(h2, b), c, false);
#else
    h2 x = __builtin_bit_cast(h2, a), y = __builtin_bit_cast(h2, b);
    return c + (float)x.x * (float)y.x + (float)x.y * (float)y.y;
#endif
}
__device__ __forceinline__ unsigned int packf16(float a, float b) {
    h2 p; p.x = (_Float16)a; p.y = (_Float16)b;
    return __builtin_bit_cast(unsigned int, p);
}
__device__ __forceinline__ float2 unpackf16(unsigned int u) {
    h2 p = __builtin_bit_cast(h2, u);
    return make_float2((float)p.x, (float)p.y);
}

// repetition macros (named vars only -- arrays get scratch-demoted, R4/R6)
#define R8(F)  F(0)F(1)F(2)F(3)F(4)F(5)F(6)F(7)
#define R28_8(F) F(8)F(9)F(10)F(11)F(12)F(13)F(14)F(15)F(16)F(17)F(18)F(19)F(20)F(21)F(22)F(23)F(24)F(25)F(26)F(27)F(28)F(29)F(30)F(31)F(32)F(33)F(34)F(35)
#define R36(F) R8(F) R28_8(F)
#define R64(F) R36(F) F(36)F(37)F(38)F(39)F(40)F(41)F(42)F(43)F(44)F(45)F(46)F(47)F(48)F(49)F(50)F(51)F(52)F(53)F(54)F(55)F(56)F(57)F(58)F(59)F(60)F(61)F(62)F(63)

#define QD(Q,i0,i1,i2,i3) { a0 = fdot2f((Q).x, w##i0, a0); a1 = fdot2f((Q).y, w##i1, a1); \
                            a2 = fdot2f((Q).z, w##i2, a2); a3 = fdot2f((Q).w, w##i3, a3); }
#define QDU(Q,i0,i1,i2,i3) { a0 = fdot2f((Q).x, u##i0, a0); a1 = fdot2f((Q).y, u##i1, a1); \
                             a2 = fdot2f((Q).z, u##i2, a2); a3 = fdot2f((Q).w, u##i3, a3); }

// ---------------- encoder ----------------
// grid 512 = batch x dir; block 1024. Row r=t&511 split: half A (t<512) owns
// [x(16)|h(0:56)], half B owns h(56:128) -> 36 named f16-pair dwords each,
// ~55 VGPR total: fits even the allocator's 64-reg target. 27KB LDS ->
// 2 blocks/CU, 8 waves/SIMD.
__global__ __launch_bounds__(1024, 2)
void enc_kernel(const float* __restrict__ x,
                const float* __restrict__ Wih_f, const float* __restrict__ Whh_f, const float* __restrict__ b_f,
                const float* __restrict__ Wih_b, const float* __restrict__ Whh_b, const float* __restrict__ b_b,
                float* __restrict__ st)   // st[b][dir][{h,c}][NH]
{
    __shared__ unsigned int xsh[TB * NI / 2];  // 5760 dw = 23KB (f16 pairs)
    __shared__ unsigned int hsh[NH / 2];       // 64 dw
    __shared__ float ps[1024];

    const int wg  = blockIdx.x;
    const int dir = wg & 1;
    const int b   = wg >> 1;
    const int t   = threadIdx.x;
    const int half = t >> 9;
    const int r    = t & 511;

    const float* Wih = dir ? Wih_b : Wih_f;
    const float* Whh = dir ? Whh_b : Whh_f;
    const float* bv  = dir ? b_b   : b_f;

    {
        const float2* xg = (const float2*)(x + (size_t)b * TB * NI);
        for (int i = t; i < TB * NI / 2; i += 1024) {
            float2 v = xg[i];
            xsh[i] = packf16(v.x, v.y);
        }
    }

#define DW(K) unsigned int w##K;
    R36(DW)
#undef DW
    float bias = 0.0f;
    if (half == 0) {
        const float* xr = Wih + r * NI;
        const float* hr = Whh + r * NH;
#define LAX(K) w##K = packf16(xr[2*(K)], xr[2*(K)+1]);
        R8(LAX)
#undef LAX
#define LAH(K) w##K = packf16(hr[2*((K)-8)], hr[2*((K)-8)+1]);
        R28_8(LAH)
#undef LAH
        bias = bv[r];
    } else {
        const float* hr = Whh + r * NH;
#define LBH(K) w##K = packf16(hr[56 + 2*(K)], hr[57 + 2*(K)]);
        R36(LBH)
#undef LBH
    }

    if (t < NH / 2) hsh[t] = 0u;
    float cc = 0.0f, hlast = 0.0f;
    __syncthreads();

    for (int s = 0; s < TB; ++s) {
        const int tt = dir ? (TB - 1 - s) : s;
        float a0 = bias, a1 = 0.f, a2 = 0.f, a3 = 0.f;
        const uint4* hv = (const uint4*)hsh;
        uint4 q;
        if (half == 0) {
            const uint4* xv = (const uint4*)(xsh + tt * 8);
            q = xv[0]; QD(q, 0, 1, 2, 3)
            q = xv[1]; QD(q, 4, 5, 6, 7)
            q = hv[0]; QD(q, 8, 9, 10, 11)
            q = hv[1]; QD(q, 12, 13, 14, 15)
            q = hv[2]; QD(q, 16, 17, 18, 19)
            q = hv[3]; QD(q, 20, 21, 22, 23)
            q = hv[4]; QD(q, 24, 25, 26, 27)
            q = hv[5]; QD(q, 28, 29, 30, 31)
            q = hv[6]; QD(q, 32, 33, 34, 35)
        } else {
            q = hv[7];  QD(q, 0, 1, 2, 3)
            q = hv[8];  QD(q, 4, 5, 6, 7)
            q = hv[9];  QD(q, 8, 9, 10, 11)
            q = hv[10]; QD(q, 12, 13, 14, 15)
            q = hv[11]; QD(q, 16, 17, 18, 19)
            q = hv[12]; QD(q, 20, 21, 22, 23)
            q = hv[13]; QD(q, 24, 25, 26, 27)
            q = hv[14]; QD(q, 28, 29, 30, 31)
            q = hv[15]; QD(q, 32, 33, 34, 35)
        }
        ps[t] = (a0 + a1) + (a2 + a3);
        __syncthreads();
        if (t < NH) {
            float gi = ps[t]       + ps[t + 512];
            float gf = ps[t + 128] + ps[t + 640];
            float gg = ps[t + 256] + ps[t + 768];
            float go = ps[t + 384] + ps[t + 896];
            cc = sigf(gf) * cc + sigf(gi) * tanhf(gg);
            hlast = sigf(go) * tanhf(cc);
            ((_Float16*)hsh)[t] = (_Float16)hlast;
        }
        __syncthreads();
    }

    if (t < NH) {
        st[((b * 2 + dir) * 2 + 0) * NH + t] = hlast;
        st[((b * 2 + dir) * 2 + 1) * NH + t] = cc;
    }
}

// ---------------- decoder ----------------
// grid 256 (one per batch elem); block 1024; cell=t>>9 (0=f,1=b), row r=t&511.
// Full 72-dw f16 row in NAMED dwords (~95 VGPR; 1 block/CU so cap 128).
__global__ __launch_bounds__(1024, 1)
void dec_kernel(const float* __restrict__ x,
                const float* __restrict__ Wih_f, const float* __restrict__ Whh_f, const float* __restrict__ b_f,
                const float* __restrict__ Wih_b, const float* __restrict__ Whh_b, const float* __restrict__ b_b,
                const float* __restrict__ Wlin, const float* __restrict__ blin,
                const float* __restrict__ st, float* __restrict__ out)
{
    __shared__ unsigned int hFh[NH / 2], hBh[NH / 2];  // h as f16 pairs
    __shared__ unsigned int inpH[NI / 2];
    __shared__ float g[1024];
    __shared__ float prt[NG];

    const int b    = blockIdx.x;
    const int t    = threadIdx.x;
    const int cell = t >> 9;
    const int r    = t & 511;

    const float* Wih = cell ? Wih_b : Wih_f;
    const float* Whh = cell ? Whh_b : Whh_f;
    const float* bv  = cell ? b_b   : b_f;

#define DW(K) unsigned int w##K;
    R64(DW)
#undef DW
#define DU(K) unsigned int u##K;
    R8(DU)
#undef DU
    {
        const float* xr = Wih + r * NI;
        const float* hr = Whh + r * NH;
#define LU(K) u##K = packf16(xr[2*(K)], xr[2*(K)+1]);
        R8(LU)
#undef LU
#define LH(K) w##K = packf16(hr[2*(K)], hr[2*(K)+1]);
        R64(LH)
#undef LH
    }
    const float bias = bv[r];

    float cc = 0.0f;
    if (t < 64) {
        const float* sh = st + ((b * 2 + 0) * 2 + 0) * NH;
        hFh[t] = packf16(sh[2 * t], sh[2 * t + 1]);
    } else if (t < 128) {
        const float* sh = st + ((b * 2 + 1) * 2 + 0) * NH;
        hBh[t - 64] = packf16(sh[2 * (t - 64)], sh[2 * (t - 64) + 1]);
    }
    if (t < NH) cc = st[((b * 2 + 0) * 2 + 1) * NH + t];
    else if (t >= 512 && t < 512 + NH) cc = st[((b * 2 + 1) * 2 + 1) * NH + (t - 512)];
    if (t < 8) {
        float2 v = ((const float2*)(x + (size_t)b * TB * NI + (TB - 1) * NI))[t];
        inpH[t] = packf16(v.x, v.y);
    }
    __syncthreads();

    for (int s = 0; s < PRED; ++s) {
        float a0 = bias, a1 = 0.f, a2 = 0.f, a3 = 0.f;
        uint4 q;
        {
            const uint4* xv = (const uint4*)inpH;
            q = xv[0]; QDU(q, 0, 1, 2, 3)
            q = xv[1]; QDU(q, 4, 5, 6, 7)
        }
        const uint4* hv = cell ? (const uint4*)hBh : (const uint4*)hFh;
        q = hv[0];  QD(q, 0, 1, 2, 3)
        q = hv[1];  QD(q, 4, 5, 6, 7)
        q = hv[2];  QD(q, 8, 9, 10, 11)
        q = hv[3];  QD(q, 12, 13, 14, 15)
        q = hv[4];  QD(q, 16, 17, 18, 19)
        q = hv[5];  QD(q, 20, 21, 22, 23)
        q = hv[6];  QD(q, 24, 25, 26, 27)
        q = hv[7];  QD(q, 28, 29, 30, 31)
        q = hv[8];  QD(q, 32, 33, 34, 35)
        q = hv[9];  QD(q, 36, 37, 38, 39)
        q = hv[10]; QD(q, 40, 41, 42, 43)
        q = hv[11]; QD(q, 44, 45, 46, 47)
        q = hv[12]; QD(q, 48, 49, 50, 51)
        q = hv[13]; QD(q, 52, 53, 54, 55)
        q = hv[14]; QD(q, 56, 57, 58, 59)
        q = hv[15]; QD(q, 60, 61, 62, 63)
        g[t] = (a0 + a1) + (a2 + a3);
        __syncthreads();
        if ((t < NH) || (t >= 512 && t < 512 + NH)) {
            float gi = g[t], gf = g[t + NH], gg = g[t + 2 * NH], go = g[t + 3 * NH];
            cc = sigf(gf) * cc + sigf(gi) * tanhf(gg);
            float h = sigf(go) * tanhf(cc);
            if (t < NH) ((_Float16*)hFh)[t] = (_Float16)h;
            else        ((_Float16*)hBh)[t - 512] = (_Float16)h;
        }
        __syncthreads();
        if (t < NG) {
            const int j = t >> 5, ch = t & 31;
            const unsigned int* hsrc = (ch < 16) ? (hFh + ch * 4) : (hBh + (ch - 16) * 4);
            const float* wl = Wlin + j * (2 * NH) + ch * 8;
            float2 v0 = unpackf16(hsrc[0]);
            float2 v1 = unpackf16(hsrc[1]);
            float2 v2 = unpackf16(hsrc[2]);
            float2 v3 = unpackf16(hsrc[3]);
            prt[t] = v0.x * wl[0] + v0.y * wl[1] + v1.x * wl[2] + v1.y * wl[3]
                   + v2.x * wl[4] + v2.y * wl[5] + v3.x * wl[6] + v3.y * wl[7];
        }
        __syncthreads();
        if (t < NI) {
            float o = blin[t];
#pragma unroll
            for (int c2 = 0; c2 < 32; ++c2) o += prt[t * 32 + c2];
            out[(size_t)b * PRED * NI + s * NI + t] = o;
            ((_Float16*)inpH)[t] = (_Float16)o;
        }
        __syncthreads();
    }
}

extern "C" void kernel_launch(void* const* d_in, const int* in_sizes, int n_in,
                              void* d_out, int out_size, void* d_ws, size_t ws_size,
                              hipStream_t stream)
{
    const float* x      = (const float*)d_in[0];
    const float* eWih_f = (const float*)d_in[1];
    const float* eWhh_f = (const float*)d_in[2];
    const float* eb_f   = (const float*)d_in[3];
    const float* eWih_b = (const float*)d_in[4];
    const float* eWhh_b = (const float*)d_in[5];
    const float* eb_b   = (const float*)d_in[6];
    const float* dWih_f = (const float*)d_in[7];
    const float* dWhh_f = (const float*)d_in[8];
    const float* db_f   = (const float*)d_in[9];
    const float* dWih_b = (const float*)d_in[10];
    const float* dWhh_b = (const float*)d_in[11];
    const float* db_b   = (const float*)d_in[12];
    const float* Wlin   = (const float*)d_in[13];
    const float* blin   = (const float*)d_in[14];

    float* st = (float*)d_ws;  // 256*2*2*128 f32 encoder final states

    enc_kernel<<<512, 1024, 0, stream>>>(x, eWih_f, eWhh_f, eb_f, eWih_b, eWhh_b, eb_b, st);
    dec_kernel<<<256, 1024, 0, stream>>>(x, dWih_f, dWhh_f, db_f, dWih_b, dWhh_b, db_b,
                                         Wlin, blin, st, (float*)d_out);
}

// Round 8
// 1332.774 us; speedup vs baseline: 1.0101x; 1.0101x over previous
//
#include <hip/hip_runtime.h>
#include <math.h>

#define TB   720
#define NI   16
#define NH   128
#define NG   512
#define PRED 96

typedef _Float16 h2 __attribute__((ext_vector_type(2)));

__device__ __forceinline__ float sigf(float v) { return 1.0f / (1.0f + __expf(-v)); }

__device__ __forceinline__ float fdot2f(unsigned int a, unsigned int b, float c) {
#if __has_builtin(__builtin_amdgcn_fdot2)
    return __builtin_amdgcn_fdot2(__builtin_bit_cast(h2, a), __builtin_bit_cast(h2, b), c, false);
#else
    h2 x = __builtin_bit_cast(h2, a), y = __builtin_bit_cast(h2, b);
    return c + (float)x.x * (float)y.x + (float)x.y * (float)y.y;
#endif
}
__device__ __forceinline__ unsigned int packf16(float a, float b) {
    h2 p; p.x = (_Float16)a; p.y = (_Float16)b;
    return __builtin_bit_cast(unsigned int, p);
}
__device__ __forceinline__ float2 unpackf16(unsigned int u) {
    h2 p = __builtin_bit_cast(h2, u);
    return make_float2((float)p.x, (float)p.y);
}

// named-var repetition macros (arrays get scratch-demoted: R4/R6 evidence)
#define R8(F)  F(0)F(1)F(2)F(3)F(4)F(5)F(6)F(7)
#define R36_(F) F(8)F(9)F(10)F(11)F(12)F(13)F(14)F(15)F(16)F(17)F(18)F(19)F(20)F(21)F(22)F(23)F(24)F(25)F(26)F(27)F(28)F(29)F(30)F(31)F(32)F(33)F(34)F(35)
#define R36(F) R8(F) R36_(F)
#define R64(F) R36(F) F(36)F(37)F(38)F(39)F(40)F(41)F(42)F(43)F(44)F(45)F(46)F(47)F(48)F(49)F(50)F(51)F(52)F(53)F(54)F(55)F(56)F(57)F(58)F(59)F(60)F(61)F(62)F(63)

#define QD(Q,i0,i1,i2,i3) { a0 = fdot2f((Q).x, w##i0, a0); a1 = fdot2f((Q).y, w##i1, a1); \
                            a2 = fdot2f((Q).z, w##i2, a2); a3 = fdot2f((Q).w, w##i3, a3); }
#define QDU(Q,i0,i1,i2,i3) { a0 = fdot2f((Q).x, u##i0, a0); a1 = fdot2f((Q).y, u##i1, a1); \
                             a2 = fdot2f((Q).z, u##i2, a2); a3 = fdot2f((Q).w, u##i3, a3); }

// wh naming: wh{J}_{K}: row-block J (0..3), col dword K (0..7)
#define FOR8J(F,J) F(J,0)F(J,1)F(J,2)F(J,3)F(J,4)F(J,5)F(J,6)F(J,7)
#define FORJK(F) FOR8J(F,0) FOR8J(F,1) FOR8J(F,2) FOR8J(F,3)

// ---------------- encoder ----------------
// grid 512 = batch x dir; block 1024 = 16 waves. Wave w: rows [32w,32w+32).
// lane = 8*ri + si. Thread owns 4 rows {32w+ri+8j} x 16 h-cols [16si..16si+16)
// + 2 x-cols [2si..2si+2): 36 named f16-pair dwords. Per step reads only its
// 16-col h-slice (2xb128) + 1 x-dword = 36B (R7 read 288B -> LDS-BW-bound at
// 4096 cyc/step). Partials -> ps[row][8]; 128 threads reduce + nonlinearity.
__global__ __launch_bounds__(1024, 2)
void enc_kernel(const float* __restrict__ x,
                const float* __restrict__ Wih_f, const float* __restrict__ Whh_f, const float* __restrict__ b_f,
                const float* __restrict__ Wih_b, const float* __restrict__ Whh_b, const float* __restrict__ b_b,
                float* __restrict__ st)   // st[b][dir][{h,c}][NH]
{
    __shared__ unsigned int xsh[TB * NI / 2];  // 5760 dw = 23KB (f16 pairs)
    __shared__ unsigned int hsh[NH / 2];       // 64 dw (128 f16)
    __shared__ float ps[NG * 8];               // 16KB partials [row][slice]

    const int wg  = blockIdx.x;
    const int dir = wg & 1;
    const int b   = wg >> 1;
    const int t   = threadIdx.x;
    const int lane = t & 63;
    const int wv   = t >> 6;
    const int si   = lane & 7;
    const int ri   = lane >> 3;
    const int rb   = wv * 32 + ri;     // base row; rows rb+8j, j=0..3

    const float* Wih = dir ? Wih_b : Wih_f;
    const float* Whh = dir ? Whh_b : Whh_f;
    const float* bv  = dir ? b_b   : b_f;

    {
        const float2* xg = (const float2*)(x + (size_t)b * TB * NI);
        for (int i = t; i < TB * NI / 2; i += 1024) {
            float2 v = xg[i];
            xsh[i] = packf16(v.x, v.y);
        }
    }

    // ---- weights: 36 named dwords ----
#define DWH(J,K) unsigned int wh##J##_##K;
    FORJK(DWH)
#undef DWH
    unsigned int wx0, wx1, wx2, wx3;
    {
        const float* hr = Whh + (size_t)rb * NH + 16 * si;
#define LWH(J,K) wh##J##_##K = packf16(hr[(J)*8*NH + 2*(K)], hr[(J)*8*NH + 2*(K) + 1]);
        FORJK(LWH)
#undef LWH
        const float* xr = Wih + (size_t)rb * NI + 2 * si;
        wx0 = packf16(xr[0*8*NI], xr[0*8*NI + 1]);
        wx1 = packf16(xr[1*8*NI], xr[1*8*NI + 1]);
        wx2 = packf16(xr[2*8*NI], xr[2*8*NI + 1]);
        wx3 = packf16(xr[3*8*NI], xr[3*8*NI + 1]);
    }
    // stage-3 biases (t<128 uses)
    const int d = t & 127;
    const float bi0 = bv[d], bi1 = bv[d + 128], bi2 = bv[d + 256], bi3 = bv[d + 384];

    if (t < NH / 2) hsh[t] = 0u;
    float cc = 0.0f, hlast = 0.0f;
    const int pbase = rb * 8 + si;
    __syncthreads();

    for (int s = 0; s < TB; ++s) {
        const int tt = dir ? (TB - 1 - s) : s;
        {
            const unsigned int xq = xsh[tt * 8 + si];
            const uint4* hv = (const uint4*)hsh;
            const uint4 q0 = hv[2 * si], q1 = hv[2 * si + 1];
#define DOTJ(J) { float a = fdot2f(xq, wx##J, 0.0f); \
            a = fdot2f(q0.x, wh##J##_0, a); a = fdot2f(q0.y, wh##J##_1, a); \
            a = fdot2f(q0.z, wh##J##_2, a); a = fdot2f(q0.w, wh##J##_3, a); \
            a = fdot2f(q1.x, wh##J##_4, a); a = fdot2f(q1.y, wh##J##_5, a); \
            a = fdot2f(q1.z, wh##J##_6, a); a = fdot2f(q1.w, wh##J##_7, a); \
            ps[pbase + (J) * 64] = a; }
            DOTJ(0) DOTJ(1) DOTJ(2) DOTJ(3)
#undef DOTJ
        }
        __syncthreads();
        if (t < NH) {
            const float4* pr = (const float4*)ps;
            float4 pa, pb;
#define SUM8 (((pa.x + pa.y) + (pa.z + pa.w)) + ((pb.x + pb.y) + (pb.z + pb.w)))
            pa = pr[t * 2];            pb = pr[t * 2 + 1];            const float gi = SUM8 + bi0;
            pa = pr[(t + 128) * 2];    pb = pr[(t + 128) * 2 + 1];    const float gf = SUM8 + bi1;
            pa = pr[(t + 256) * 2];    pb = pr[(t + 256) * 2 + 1];    const float gg = SUM8 + bi2;
            pa = pr[(t + 384) * 2];    pb = pr[(t + 384) * 2 + 1];    const float go = SUM8 + bi3;
#undef SUM8
            cc = sigf(gf) * cc + sigf(gi) * tanhf(gg);
            hlast = sigf(go) * tanhf(cc);
            ((_Float16*)hsh)[t] = (_Float16)hlast;
        }
        __syncthreads();
    }

    if (t < NH) {
        st[((b * 2 + dir) * 2 + 0) * NH + t] = hlast;
        st[((b * 2 + dir) * 2 + 1) * NH + t] = cc;
    }
}

// ---------------- decoder (R7: ~128 us, unchanged) ----------------
__global__ __launch_bounds__(1024, 1)
void dec_kernel(const float* __restrict__ x,
                const float* __restrict__ Wih_f, const float* __restrict__ Whh_f, const float* __restrict__ b_f,
                const float* __restrict__ Wih_b, const float* __restrict__ Whh_b, const float* __restrict__ b_b,
                const float* __restrict__ Wlin, const float* __restrict__ blin,
                const float* __restrict__ st, float* __restrict__ out)
{
    __shared__ unsigned int hFh[NH / 2], hBh[NH / 2];
    __shared__ unsigned int inpH[NI / 2];
    __shared__ float g[1024];
    __shared__ float prt[NG];

    const int b    = blockIdx.x;
    const int t    = threadIdx.x;
    const int cell = t >> 9;
    const int r    = t & 511;

    const float* Wih = cell ? Wih_b : Wih_f;
    const float* Whh = cell ? Whh_b : Whh_f;
    const float* bv  = cell ? b_b   : b_f;

#define DW(K) unsigned int w##K;
    R64(DW)
#undef DW
#define DU(K) unsigned int u##K;
    R8(DU)
#undef DU
    {
        const float* xr = Wih + r * NI;
        const float* hr = Whh + r * NH;
#define LU(K) u##K = packf16(xr[2*(K)], xr[2*(K)+1]);
        R8(LU)
#undef LU
#define LH(K) w##K = packf16(hr[2*(K)], hr[2*(K)+1]);
        R64(LH)
#undef LH
    }
    const float bias = bv[r];

    float cc = 0.0f;
    if (t < 64) {
        const float* sh = st + ((b * 2 + 0) * 2 + 0) * NH;
        hFh[t] = packf16(sh[2 * t], sh[2 * t + 1]);
    } else if (t < 128) {
        const float* sh = st + ((b * 2 + 1) * 2 + 0) * NH;
        hBh[t - 64] = packf16(sh[2 * (t - 64)], sh[2 * (t - 64) + 1]);
    }
    if (t < NH) cc = st[((b * 2 + 0) * 2 + 1) * NH + t];
    else if (t >= 512 && t < 512 + NH) cc = st[((b * 2 + 1) * 2 + 1) * NH + (t - 512)];
    if (t < 8) {
        float2 v = ((const float2*)(x + (size_t)b * TB * NI + (TB - 1) * NI))[t];
        inpH[t] = packf16(v.x, v.y);
    }
    __syncthreads();

    for (int s = 0; s < PRED; ++s) {
        float a0 = bias, a1 = 0.f, a2 = 0.f, a3 = 0.f;
        uint4 q;
        {
            const uint4* xv = (const uint4*)inpH;
            q = xv[0]; QDU(q, 0, 1, 2, 3)
            q = xv[1]; QDU(q, 4, 5, 6, 7)
        }
        const uint4* hv = cell ? (const uint4*)hBh : (const uint4*)hFh;
        q = hv[0];  QD(q, 0, 1, 2, 3)
        q = hv[1];  QD(q, 4, 5, 6, 7)
        q = hv[2];  QD(q, 8, 9, 10, 11)
        q = hv[3];  QD(q, 12, 13, 14, 15)
        q = hv[4];  QD(q, 16, 17, 18, 19)
        q = hv[5];  QD(q, 20, 21, 22, 23)
        q = hv[6];  QD(q, 24, 25, 26, 27)
        q = hv[7];  QD(q, 28, 29, 30, 31)
        q = hv[8];  QD(q, 32, 33, 34, 35)
        q = hv[9];  QD(q, 36, 37, 38, 39)
        q = hv[10]; QD(q, 40, 41, 42, 43)
        q = hv[11]; QD(q, 44, 45, 46, 47)
        q = hv[12]; QD(q, 48, 49, 50, 51)
        q = hv[13]; QD(q, 52, 53, 54, 55)
        q = hv[14]; QD(q, 56, 57, 58, 59)
        q = hv[15]; QD(q, 60, 61, 62, 63)
        g[t] = (a0 + a1) + (a2 + a3);
        __syncthreads();
        if ((t < NH) || (t >= 512 && t < 512 + NH)) {
            float gi = g[t], gf = g[t + NH], gg = g[t + 2 * NH], go = g[t + 3 * NH];
            cc = sigf(gf) * cc + sigf(gi) * tanhf(gg);
            float h = sigf(go) * tanhf(cc);
            if (t < NH) ((_Float16*)hFh)[t] = (_Float16)h;
            else        ((_Float16*)hBh)[t - 512] = (_Float16)h;
        }
        __syncthreads();
        if (t < NG) {
            const int j = t >> 5, ch = t & 31;
            const unsigned int* hsrc = (ch < 16) ? (hFh + ch * 4) : (hBh + (ch - 16) * 4);
            const float* wl = Wlin + j * (2 * NH) + ch * 8;
            float2 v0 = unpackf16(hsrc[0]);
            float2 v1 = unpackf16(hsrc[1]);
            float2 v2 = unpackf16(hsrc[2]);
            float2 v3 = unpackf16(hsrc[3]);
            prt[t] = v0.x * wl[0] + v0.y * wl[1] + v1.x * wl[2] + v1.y * wl[3]
                   + v2.x * wl[4] + v2.y * wl[5] + v3.x * wl[6] + v3.y * wl[7];
        }
        __syncthreads();
        if (t < NI) {
            float o = blin[t];
#pragma unroll
            for (int c2 = 0; c2 < 32; ++c2) o += prt[t * 32 + c2];
            out[(size_t)b * PRED * NI + s * NI + t] = o;
            ((_Float16*)inpH)[t] = (_Float16)o;
        }
        __syncthreads();
    }
}

extern "C" void kernel_launch(void* const* d_in, const int* in_sizes, int n_in,
                              void* d_out, int out_size, void* d_ws, size_t ws_size,
                              hipStream_t stream)
{
    const float* x      = (const float*)d_in[0];
    const float* eWih_f = (const float*)d_in[1];
    const float* eWhh_f = (const float*)d_in[2];
    const float* eb_f   = (const float*)d_in[3];
    const float* eWih_b = (const float*)d_in[4];
    const float* eWhh_b = (const float*)d_in[5];
    const float* eb_b   = (const float*)d_in[6];
    const float* dWih_f = (const float*)d_in[7];
    const float* dWhh_f = (const float*)d_in[8];
    const float* db_f   = (const float*)d_in[9];
    const float* dWih_b = (const float*)d_in[10];
    const float* dWhh_b = (const float*)d_in[11];
    const float* db_b   = (const float*)d_in[12];
    const float* Wlin   = (const float*)d_in[13];
    const float* blin   = (const float*)d_in[14];

    float* st = (float*)d_ws;  // 256*2*2*128 f32 encoder final states

    enc_kernel<<<512, 1024, 0, stream>>>(x, eWih_f, eWhh_f, eb_f, eWih_b, eWhh_b, eb_b, st);
    dec_kernel<<<256, 1024, 0, stream>>>(x, dWih_f, dWhh_f, db_f, dWih_b, dWhh_b, db_b,
                                         Wlin, blin, st, (float*)d_out);
}

// Round 9
// 1330.745 us; speedup vs baseline: 1.0116x; 1.0015x over previous
//
#include <hip/hip_runtime.h>
#include <math.h>

#define TB   720
#define NI   16
#define NH   128
#define NG   512
#define PRED 96

typedef _Float16 h2    __attribute__((ext_vector_type(2)));
typedef _Float16 f16x4 __attribute__((ext_vector_type(4)));
typedef _Float16 f16x8 __attribute__((ext_vector_type(8)));
typedef float    f32x4 __attribute__((ext_vector_type(4)));

__device__ __forceinline__ float sigf(float v) { return 1.0f / (1.0f + __expf(-v)); }
__device__ __forceinline__ float tanhfast(float v) { return 1.0f - 2.0f / (1.0f + __expf(2.0f * v)); }

__device__ __forceinline__ float fdot2f(unsigned int a, unsigned int b, float c) {
#if __has_builtin(__builtin_amdgcn_fdot2)
    return __builtin_amdgcn_fdot2(__builtin_bit_cast(h2, a), __builtin_bit_cast(h2, b), c, false);
#else
    h2 x = __builtin_bit_cast(h2, a), y = __builtin_bit_cast(h2, b);
    return c + (float)x.x * (float)y.x + (float)x.y * (float)y.y;
#endif
}
__device__ __forceinline__ unsigned int packf16(float a, float b) {
    h2 p; p.x = (_Float16)a; p.y = (_Float16)b;
    return __builtin_bit_cast(unsigned int, p);
}
__device__ __forceinline__ float2 unpackf16(unsigned int u) {
    h2 p = __builtin_bit_cast(h2, u);
    return make_float2((float)p.x, (float)p.y);
}

// build A/B frag with split-half k layout: elem j -> k = (j>>2)*16 + (j&3) rel. to p
__device__ __forceinline__ f16x8 mk8(const float* p) {
    f16x8 v;
    v[0] = (_Float16)p[0];  v[1] = (_Float16)p[1];  v[2] = (_Float16)p[2];  v[3] = (_Float16)p[3];
    v[4] = (_Float16)p[16]; v[5] = (_Float16)p[17]; v[6] = (_Float16)p[18]; v[7] = (_Float16)p[19];
    return v;
}
__device__ __forceinline__ f16x8 mkx(float4 q) {  // x frag: real k<16 half, zero k>=16 half
    f16x8 v;
    v[0] = (_Float16)q.x; v[1] = (_Float16)q.y; v[2] = (_Float16)q.z; v[3] = (_Float16)q.w;
    v[4] = (_Float16)0.f; v[5] = (_Float16)0.f; v[6] = (_Float16)0.f; v[7] = (_Float16)0.f;
    return v;
}
__device__ __forceinline__ f32x4 MFMA(f16x8 a, f16x8 b, f32x4 c) {
    return __builtin_amdgcn_mfma_f32_16x16x32_f16(a, b, c, 0, 0, 0);
}

// ---------------- encoder (MFMA) ----------------
// grid 32 = (batch/16) x dir; block 1024 = 16 waves. GEMM per step:
// gates'[512 perm rows][16 batch] = W'[512][K] @ [x|h]^T, K = 32(pad) + 128.
// W' rows permuted R=4d+g so each lane's 4 C-regs = (i,f,g,o) of one (d,batch)
// (m89 C layout: col=lane&15, row=(lane>>4)*4+reg). W static in A-frags
// (36 dw/thread); h in 4KB XOR-swizzled LDS; x global w/ prefetch.
__global__ __launch_bounds__(1024, 1)
void enc_kernel(const float* __restrict__ x,
                const float* __restrict__ Wih_f, const float* __restrict__ Whh_f, const float* __restrict__ b_f,
                const float* __restrict__ Wih_b, const float* __restrict__ Whh_b, const float* __restrict__ b_b,
                float* __restrict__ st)   // st[b][dir][{h,c}][NH]
{
    __shared__ _Float16 hlds[16 * NH];   // [batch16][d128] f16, byte ^= (batch&7)<<4

    const int blk = blockIdx.x;
    const int dir = blk & 1;
    const int b0  = (blk >> 1) << 4;
    const int t   = threadIdx.x;
    const int wv  = t >> 6;
    const int l   = t & 63;
    const int lr  = l & 15;    // A row-in-tile / B,C col (batch)
    const int lk  = l >> 4;    // k-group

    const float* Wih = dir ? Wih_b : Wih_f;
    const float* Whh = dir ? Whh_b : Whh_f;
    const float* bv  = dir ? b_b   : b_f;

    // ---- static A-frags: m-tiles 2wv, 2wv+1; row R=mt*16+lr; orig=(R&3)*128+(R>>2)
    const int R0  = (2 * wv) * 16 + lr;
    const int or0 = (R0 & 3) * 128 + (R0 >> 2);
    const int R1  = (2 * wv + 1) * 16 + lr;
    const int or1 = (R1 & 3) * 128 + (R1 >> 2);
    const float* h0p = Whh + (size_t)or0 * NH + lk * 4;
    const float* h1p = Whh + (size_t)or1 * NH + lk * 4;
    f16x8 wh0_0 = mk8(h0p), wh0_1 = mk8(h0p + 32), wh0_2 = mk8(h0p + 64), wh0_3 = mk8(h0p + 96);
    f16x8 wh1_0 = mk8(h1p), wh1_1 = mk8(h1p + 32), wh1_2 = mk8(h1p + 64), wh1_3 = mk8(h1p + 96);
    f16x8 wx0, wx1;
    {
        float4 q0 = *(const float4*)(Wih + (size_t)or0 * NI + lk * 4);
        float4 q1 = *(const float4*)(Wih + (size_t)or1 * NI + lk * 4);
        wx0 = mkx(q0); wx1 = mkx(q1);
    }
    const int d0g = (2 * wv) * 4 + lk;
    const int d1g = (2 * wv + 1) * 4 + lk;
    const float bi00 = bv[d0g], bi01 = bv[128 + d0g], bi02 = bv[256 + d0g], bi03 = bv[384 + d0g];
    const float bi10 = bv[d1g], bi11 = bv[128 + d1g], bi12 = bv[256 + d1g], bi13 = bv[384 + d1g];

    // init h = 0 (2048 f16 = 1024 dw)
    ((unsigned int*)hlds)[t] = 0u;
    float cs0 = 0.f, cs1 = 0.f, hv0 = 0.f, hv1 = 0.f;

    // x prefetch (lane: batch lr, cols lk*4..+4)
    const size_t xrow = (size_t)(b0 + lr) * TB;
    int tt = dir ? (TB - 1) : 0;
    float4 xcur = *(const float4*)(x + (xrow + tt) * NI + lk * 4);
    __syncthreads();

    const int swz = (lr & 7) << 4;
    for (int s = 0; s < TB; ++s) {
        // B h-frags from LDS (written last step), split-half k layout
        f16x8 bh0, bh1, bh2, bh3;
        {
#define RDBH(DST, KS) { \
            int ba_ = ((lr << 8) + (((KS) * 32 + lk * 4) << 1)) ^ swz; \
            int bb_ = ((lr << 8) + (((KS) * 32 + lk * 4 + 16) << 1)) ^ swz; \
            f16x4 lo_ = *(const f16x4*)((const char*)hlds + ba_); \
            f16x4 hi_ = *(const f16x4*)((const char*)hlds + bb_); \
            DST = __builtin_shufflevector(lo_, hi_, 0, 1, 2, 3, 4, 5, 6, 7); }
            RDBH(bh0, 0) RDBH(bh1, 1) RDBH(bh2, 2) RDBH(bh3, 3)
#undef RDBH
        }
        f16x8 bx = mkx(xcur);
        // prefetch next x
        {
            int sn = (s + 1 < TB) ? s + 1 : TB - 1;
            int ttn = dir ? (TB - 1 - sn) : sn;
            xcur = *(const float4*)(x + (xrow + ttn) * NI + lk * 4);
        }
        __syncthreads();   // all h reads done before overwrites

        f32x4 C0 = {0.f, 0.f, 0.f, 0.f};
        f32x4 C1 = {0.f, 0.f, 0.f, 0.f};
        C0 = MFMA(wx0, bx, C0);
        C0 = MFMA(wh0_0, bh0, C0); C0 = MFMA(wh0_1, bh1, C0);
        C0 = MFMA(wh0_2, bh2, C0); C0 = MFMA(wh0_3, bh3, C0);
        C1 = MFMA(wx1, bx, C1);
        C1 = MFMA(wh1_0, bh0, C1); C1 = MFMA(wh1_1, bh1, C1);
        C1 = MFMA(wh1_2, bh2, C1); C1 = MFMA(wh1_3, bh3, C1);

        // nonlinearity: lane's 4 regs = (i,f,g,o) of (d, batch=lr)
        {
            float gi = C0[0] + bi00, gf = C0[1] + bi01, gg = C0[2] + bi02, go = C0[3] + bi03;
            cs0 = sigf(gf) * cs0 + sigf(gi) * tanhfast(gg);
            hv0 = sigf(go) * tanhfast(cs0);
            int wb = ((lr << 8) + (d0g << 1)) ^ swz;
            *(_Float16*)((char*)hlds + wb) = (_Float16)hv0;
        }
        {
            float gi = C1[0] + bi10, gf = C1[1] + bi11, gg = C1[2] + bi12, go = C1[3] + bi13;
            cs1 = sigf(gf) * cs1 + sigf(gi) * tanhfast(gg);
            hv1 = sigf(go) * tanhfast(cs1);
            int wb = ((lr << 8) + (d1g << 1)) ^ swz;
            *(_Float16*)((char*)hlds + wb) = (_Float16)hv1;
        }
        __syncthreads();   // h visible for next step
    }

    // final states (f32)
    {
        const size_t base = ((size_t)(b0 + lr) * 2 + dir) * 2 * NH;
        st[base + d0g]      = hv0;
        st[base + NH + d0g] = cs0;
        st[base + d1g]      = hv1;
        st[base + NH + d1g] = cs1;
    }
}

// named-var repetition macros (arrays get scratch-demoted: R4/R6 evidence)
#define R8(F)  F(0)F(1)F(2)F(3)F(4)F(5)F(6)F(7)
#define R36_(F) F(8)F(9)F(10)F(11)F(12)F(13)F(14)F(15)F(16)F(17)F(18)F(19)F(20)F(21)F(22)F(23)F(24)F(25)F(26)F(27)F(28)F(29)F(30)F(31)F(32)F(33)F(34)F(35)
#define R36(F) R8(F) R36_(F)
#define R64(F) R36(F) F(36)F(37)F(38)F(39)F(40)F(41)F(42)F(43)F(44)F(45)F(46)F(47)F(48)F(49)F(50)F(51)F(52)F(53)F(54)F(55)F(56)F(57)F(58)F(59)F(60)F(61)F(62)F(63)

#define QD(Q,i0,i1,i2,i3) { a0 = fdot2f((Q).x, w##i0, a0); a1 = fdot2f((Q).y, w##i1, a1); \
                            a2 = fdot2f((Q).z, w##i2, a2); a3 = fdot2f((Q).w, w##i3, a3); }
#define QDU(Q,i0,i1,i2,i3) { a0 = fdot2f((Q).x, u##i0, a0); a1 = fdot2f((Q).y, u##i1, a1); \
                             a2 = fdot2f((Q).z, u##i2, a2); a3 = fdot2f((Q).w, u##i3, a3); }

// ---------------- decoder (R7 known-good, ~135 us) ----------------
__global__ __launch_bounds__(1024, 1)
void dec_kernel(const float* __restrict__ x,
                const float* __restrict__ Wih_f, const float* __restrict__ Whh_f, const float* __restrict__ b_f,
                const float* __restrict__ Wih_b, const float* __restrict__ Whh_b, const float* __restrict__ b_b,
                const float* __restrict__ Wlin, const float* __restrict__ blin,
                const float* __restrict__ st, float* __restrict__ out)
{
    __shared__ unsigned int hFh[NH / 2], hBh[NH / 2];
    __shared__ unsigned int inpH[NI / 2];
    __shared__ float g[1024];
    __shared__ float prt[NG];

    const int b    = blockIdx.x;
    const int t    = threadIdx.x;
    const int cell = t >> 9;
    const int r    = t & 511;

    const float* Wih = cell ? Wih_b : Wih_f;
    const float* Whh = cell ? Whh_b : Whh_f;
    const float* bv  = cell ? b_b   : b_f;

#define DW(K) unsigned int w##K;
    R64(DW)
#undef DW
#define DU(K) unsigned int u##K;
    R8(DU)
#undef DU
    {
        const float* xr = Wih + r * NI;
        const float* hr = Whh + r * NH;
#define LU(K) u##K = packf16(xr[2*(K)], xr[2*(K)+1]);
        R8(LU)
#undef LU
#define LH(K) w##K = packf16(hr[2*(K)], hr[2*(K)+1]);
        R64(LH)
#undef LH
    }
    const float bias = bv[r];

    float cc = 0.0f;
    if (t < 64) {
        const float* sh = st + ((b * 2 + 0) * 2 + 0) * NH;
        hFh[t] = packf16(sh[2 * t], sh[2 * t + 1]);
    } else if (t < 128) {
        const float* sh = st + ((b * 2 + 1) * 2 + 0) * NH;
        hBh[t - 64] = packf16(sh[2 * (t - 64)], sh[2 * (t - 64) + 1]);
    }
    if (t < NH) cc = st[((b * 2 + 0) * 2 + 1) * NH + t];
    else if (t >= 512 && t < 512 + NH) cc = st[((b * 2 + 1) * 2 + 1) * NH + (t - 512)];
    if (t < 8) {
        float2 v = ((const float2*)(x + (size_t)b * TB * NI + (TB - 1) * NI))[t];
        inpH[t] = packf16(v.x, v.y);
    }
    __syncthreads();

    for (int s = 0; s < PRED; ++s) {
        float a0 = bias, a1 = 0.f, a2 = 0.f, a3 = 0.f;
        uint4 q;
        {
            const uint4* xv = (const uint4*)inpH;
            q = xv[0]; QDU(q, 0, 1, 2, 3)
            q = xv[1]; QDU(q, 4, 5, 6, 7)
        }
        const uint4* hv = cell ? (const uint4*)hBh : (const uint4*)hFh;
        q = hv[0];  QD(q, 0, 1, 2, 3)
        q = hv[1];  QD(q, 4, 5, 6, 7)
        q = hv[2];  QD(q, 8, 9, 10, 11)
        q = hv[3];  QD(q, 12, 13, 14, 15)
        q = hv[4];  QD(q, 16, 17, 18, 19)
        q = hv[5];  QD(q, 20, 21, 22, 23)
        q = hv[6];  QD(q, 24, 25, 26, 27)
        q = hv[7];  QD(q, 28, 29, 30, 31)
        q = hv[8];  QD(q, 32, 33, 34, 35)
        q = hv[9];  QD(q, 36, 37, 38, 39)
        q = hv[10]; QD(q, 40, 41, 42, 43)
        q = hv[11]; QD(q, 44, 45, 46, 47)
        q = hv[12]; QD(q, 48, 49, 50, 51)
        q = hv[13]; QD(q, 52, 53, 54, 55)
        q = hv[14]; QD(q, 56, 57, 58, 59)
        q = hv[15]; QD(q, 60, 61, 62, 63)
        g[t] = (a0 + a1) + (a2 + a3);
        __syncthreads();
        if ((t < NH) || (t >= 512 && t < 512 + NH)) {
            float gi = g[t], gf = g[t + NH], gg = g[t + 2 * NH], go = g[t + 3 * NH];
            cc = sigf(gf) * cc + sigf(gi) * tanhf(gg);
            float h = sigf(go) * tanhf(cc);
            if (t < NH) ((_Float16*)hFh)[t] = (_Float16)h;
            else        ((_Float16*)hBh)[t - 512] = (_Float16)h;
        }
        __syncthreads();
        if (t < NG) {
            const int j = t >> 5, ch = t & 31;
            const unsigned int* hsrc = (ch < 16) ? (hFh + ch * 4) : (hBh + (ch - 16) * 4);
            const float* wl = Wlin + j * (2 * NH) + ch * 8;
            float2 v0 = unpackf16(hsrc[0]);
            float2 v1 = unpackf16(hsrc[1]);
            float2 v2 = unpackf16(hsrc[2]);
            float2 v3 = unpackf16(hsrc[3]);
            prt[t] = v0.x * wl[0] + v0.y * wl[1] + v1.x * wl[2] + v1.y * wl[3]
                   + v2.x * wl[4] + v2.y * wl[5] + v3.x * wl[6] + v3.y * wl[7];
        }
        __syncthreads();
        if (t < NI) {
            float o = blin[t];
#pragma unroll
            for (int c2 = 0; c2 < 32; ++c2) o += prt[t * 32 + c2];
            out[(size_t)b * PRED * NI + s * NI + t] = o;
            ((_Float16*)inpH)[t] = (_Float16)o;
        }
        __syncthreads();
    }
}

extern "C" void kernel_launch(void* const* d_in, const int* in_sizes, int n_in,
                              void* d_out, int out_size, void* d_ws, size_t ws_size,
                              hipStream_t stream)
{
    const float* x      = (const float*)d_in[0];
    const float* eWih_f = (const float*)d_in[1];
    const float* eWhh_f = (const float*)d_in[2];
    const float* eb_f   = (const float*)d_in[3];
    const float* eWih_b = (const float*)d_in[4];
    const float* eWhh_b = (const float*)d_in[5];
    const float* eb_b   = (const float*)d_in[6];
    const float* dWih_f = (const float*)d_in[7];
    const float* dWhh_f = (const float*)d_in[8];
    const float* db_f   = (const float*)d_in[9];
    const float* dWih_b = (const float*)d_in[10];
    const float* dWhh_b = (const float*)d_in[11];
    const float* db_b   = (const float*)d_in[12];
    const float* Wlin   = (const float*)d_in[13];
    const float* blin   = (const float*)d_in[14];

    float* st = (float*)d_ws;  // 256*2*2*128 f32 encoder final states

    enc_kernel<<<32, 1024, 0, stream>>>(x, eWih_f, eWhh_f, eb_f, eWih_b, eWhh_b, eb_b, st);
    dec_kernel<<<256, 1024, 0, stream>>>(x, dWih_f, dWhh_f, db_f, dWih_b, dWhh_b, db_b,
                                         Wlin, blin, st, (float*)d_out);
}

// Round 10
// 967.583 us; speedup vs baseline: 1.3913x; 1.3753x over previous
//
#include <hip/hip_runtime.h>
#include <math.h>

#define TB   720
#define NI   16
#define NH   128
#define NG   512
#define PRED 96

typedef _Float16 h2    __attribute__((ext_vector_type(2)));
typedef _Float16 f16x4 __attribute__((ext_vector_type(4)));
typedef _Float16 f16x8 __attribute__((ext_vector_type(8)));
typedef float    f32x4 __attribute__((ext_vector_type(4)));

__device__ __forceinline__ float rcpf_(float v) {
#if __has_builtin(__builtin_amdgcn_rcpf)
    return __builtin_amdgcn_rcpf(v);
#else
    return 1.0f / v;
#endif
}
// sigmoid / tanh via v_exp + v_rcp (no IEEE div sequence, no libm tanh)
__device__ __forceinline__ float sigf(float v)   { return rcpf_(1.0f + __expf(-v)); }
__device__ __forceinline__ float tanhf_(float v) { return 1.0f - 2.0f * rcpf_(1.0f + __expf(2.0f * v)); }

__device__ __forceinline__ unsigned int packf16(float a, float b) {
    h2 p; p.x = (_Float16)a; p.y = (_Float16)b;
    return __builtin_bit_cast(unsigned int, p);
}
__device__ __forceinline__ float2 unpackf16(unsigned int u) {
    h2 p = __builtin_bit_cast(h2, u);
    return make_float2((float)p.x, (float)p.y);
}
__device__ __forceinline__ float fdot2f(unsigned int a, unsigned int b, float c) {
#if __has_builtin(__builtin_amdgcn_fdot2)
    return __builtin_amdgcn_fdot2(__builtin_bit_cast(h2, a), __builtin_bit_cast(h2, b), c, false);
#else
    h2 x = __builtin_bit_cast(h2, a), y = __builtin_bit_cast(h2, b);
    return c + (float)x.x * (float)y.x + (float)x.y * (float)y.y;
#endif
}

// A/B frag split-half k layout (verified R9): elem j -> k = (j>>2)*16 + lk*4 + (j&3)
__device__ __forceinline__ f16x8 mk8(const float* p) {
    f16x8 v;
    v[0] = (_Float16)p[0];  v[1] = (_Float16)p[1];  v[2] = (_Float16)p[2];  v[3] = (_Float16)p[3];
    v[4] = (_Float16)p[16]; v[5] = (_Float16)p[17]; v[6] = (_Float16)p[18]; v[7] = (_Float16)p[19];
    return v;
}
__device__ __forceinline__ f32x4 MFMA(f16x8 a, f16x8 b, f32x4 c) {
    return __builtin_amdgcn_mfma_f32_16x16x32_f16(a, b, c, 0, 0, 0);
}
// block LLVM from hoisting a loop-invariant LDS offset (hoist->spill hazard)
__device__ __forceinline__ int opaque(int v) { asm volatile("" : "+v"(v)); return v; }

// ---------------- encoder (MFMA, 512thr) ----------------
// grid 32 = (batch/16) x dir; block 512 = 8 waves; wave owns 4 m-tiles.
// Per step: gates'[512][16b] = W'[512][K=32pad+128] @ [x;1|h]^T.
// Row perm R=4d+g => lane (lr,lk) C regs of m-tile mt = 4 gates of cell
// (d=mt*4+lk, batch=lr). h-weights: 16 f16x8 frags in VGPR (64 regs; 512thr
// blocks get the 124-VGPR budget - R2/R9 evidence). x-weights+bias: LDS,
// re-read per step via opaque() so they can't hoist+spill. Bias enters via
// k=16 ones-column of the x-MFMA. h double-buffered -> 1 barrier/step.
__global__ __launch_bounds__(512, 1)
void enc_kernel(const float* __restrict__ x,
                const float* __restrict__ Wih_f, const float* __restrict__ Whh_f, const float* __restrict__ b_f,
                const float* __restrict__ Wih_b, const float* __restrict__ Whh_b, const float* __restrict__ b_b,
                float* __restrict__ st)   // st[b][dir][{h,c}][NH]
{
    __shared__ _Float16 hbuf0[16 * NH];        // 4KB, byte ^= (lr&7)<<4
    __shared__ _Float16 hbuf1[16 * NH];        // 4KB
    __shared__ unsigned int wxl[NG * 8];       // Wih' f16 pairs, PERM-row layout, 16KB
    __shared__ _Float16 bl[NG];                // bias f16, PERM-row layout, 1KB

    const int blk = blockIdx.x;
    const int dir = blk & 1;
    const int b0  = (blk >> 1) << 4;
    const int t   = threadIdx.x;
    const int wv  = t >> 6;
    const int l   = t & 63;
    const int lr  = l & 15;
    const int lk  = l >> 4;

    const float* Wih = dir ? Wih_b : Wih_f;
    const float* Whh = dir ? Whh_b : Whh_f;
    const float* bv  = dir ? b_b   : b_f;

    // stage Wih'/bias at PERM row index R = (o&127)*4 + (o>>7)  (o = orig row)
    {
        const int o = t, R = (o & 127) * 4 + (o >> 7);
        const float* src = Wih + (size_t)o * NI;
#pragma unroll
        for (int k2 = 0; k2 < 8; ++k2) wxl[R * 8 + k2] = packf16(src[2 * k2], src[2 * k2 + 1]);
        bl[R] = (_Float16)bv[o];
    }

    // ---- static A-h frags: 16 named f16x8 (4 m-tiles x 4 k-frags) ----
    const int mt0 = wv * 4, mt1 = wv * 4 + 1, mt2 = wv * 4 + 2, mt3 = wv * 4 + 3;
    const int R0 = mt0 * 16 + lr, R1 = mt1 * 16 + lr, R2 = mt2 * 16 + lr, R3 = mt3 * 16 + lr;
    const int or0 = (R0 & 3) * 128 + (R0 >> 2);
    const int or1 = (R1 & 3) * 128 + (R1 >> 2);
    const int or2 = (R2 & 3) * 128 + (R2 >> 2);
    const int or3 = (R3 & 3) * 128 + (R3 >> 2);
    const float* p0 = Whh + (size_t)or0 * NH + lk * 4;
    const float* p1 = Whh + (size_t)or1 * NH + lk * 4;
    const float* p2 = Whh + (size_t)or2 * NH + lk * 4;
    const float* p3 = Whh + (size_t)or3 * NH + lk * 4;
    f16x8 w0_0 = mk8(p0), w0_1 = mk8(p0 + 32), w0_2 = mk8(p0 + 64), w0_3 = mk8(p0 + 96);
    f16x8 w1_0 = mk8(p1), w1_1 = mk8(p1 + 32), w1_2 = mk8(p1 + 64), w1_3 = mk8(p1 + 96);
    f16x8 w2_0 = mk8(p2), w2_1 = mk8(p2 + 32), w2_2 = mk8(p2 + 64), w2_3 = mk8(p2 + 96);
    f16x8 w3_0 = mk8(p3), w3_1 = mk8(p3 + 32), w3_2 = mk8(p3 + 64), w3_3 = mk8(p3 + 96);

    const int d0 = mt0 * 4 + lk, d1 = mt1 * 4 + lk, d2 = mt2 * 4 + lk, d3 = mt3 * 4 + lk;

    // zero h buffer 0 (1024 dw over 512 threads)
    ((unsigned int*)hbuf0)[t] = 0u;
    ((unsigned int*)hbuf0)[t + 512] = 0u;
    float cs0 = 0.f, cs1 = 0.f, cs2 = 0.f, cs3 = 0.f;

    // x prefetch: batch lr, cols lk*4..+3
    const size_t xrow = (size_t)(b0 + lr) * TB;
    float4 xcur = *(const float4*)(x + (xrow + (dir ? TB - 1 : 0)) * NI + lk * 4);
    __syncthreads();

    const int swz   = (lr & 7) << 4;
    const int one16 = (lk == 0) ? 0x3c00 : 0;   // f16 1.0 in elem4 slot (k==16)
    const int xo0 = R0 * 32 + lk * 8, xo1 = R1 * 32 + lk * 8;
    const int xo2 = R2 * 32 + lk * 8, xo3 = R3 * 32 + lk * 8;

    for (int s = 0; s < TB; ++s) {
        const _Float16* hr = (s & 1) ? hbuf1 : hbuf0;
        _Float16*       hw = (s & 1) ? hbuf0 : hbuf1;

        // B h-frags (split-half k layout) from prev-step buffer
        f16x8 bh0, bh1, bh2, bh3;
#define RDBH(DST, KS) { \
        int ba_ = ((lr << 8) + (((KS) * 32 + lk * 4) << 1)) ^ swz; \
        int bb_ = ((lr << 8) + (((KS) * 32 + lk * 4 + 16) << 1)) ^ swz; \
        f16x4 lo_ = *(const f16x4*)((const char*)hr + ba_); \
        f16x4 hi_ = *(const f16x4*)((const char*)hr + bb_); \
        DST = __builtin_shufflevector(lo_, hi_, 0, 1, 2, 3, 4, 5, 6, 7); }
        RDBH(bh0, 0) RDBH(bh1, 1) RDBH(bh2, 2) RDBH(bh3, 3)
#undef RDBH

        // A-x frags from LDS (opaque offsets: prevent hoist->spill) + bias in elem4
        f16x8 ax0, ax1, ax2, ax3;
#define MKAX(DST, OFF, RR) { \
        f16x4 lo_ = *(const f16x4*)((const char*)wxl + opaque(OFF)); \
        unsigned int bh_ = (lk == 0) ? (unsigned int)__builtin_bit_cast(unsigned short, bl[opaque(RR)]) : 0u; \
        f16x4 hi_; *(unsigned int*)&hi_ = bh_; ((unsigned int*)&hi_)[1] = 0u; \
        DST = __builtin_shufflevector(lo_, hi_, 0, 1, 2, 3, 4, 5, 6, 7); }
        MKAX(ax0, xo0, R0) MKAX(ax1, xo1, R1) MKAX(ax2, xo2, R2) MKAX(ax3, xo3, R3)
#undef MKAX

        // B-x frag: x in k<16, 1.0 at k==16 (lane lk==0 elem4)
        f16x8 bx;
        bx[0] = (_Float16)xcur.x; bx[1] = (_Float16)xcur.y;
        bx[2] = (_Float16)xcur.z; bx[3] = (_Float16)xcur.w;
        { unsigned int u1 = (unsigned int)one16; f16x4 hi_; *(unsigned int*)&hi_ = u1; ((unsigned int*)&hi_)[1] = 0u;
          bx[4] = hi_[0]; bx[5] = hi_[1]; bx[6] = hi_[2]; bx[7] = hi_[3]; }

        // prefetch next x
        {
            int sn = (s + 1 < TB) ? s + 1 : TB - 1;
            xcur = *(const float4*)(x + (xrow + (dir ? TB - 1 - sn : sn)) * NI + lk * 4);
        }

        f32x4 C0 = {0.f,0.f,0.f,0.f}, C1 = {0.f,0.f,0.f,0.f};
        f32x4 C2 = {0.f,0.f,0.f,0.f}, C3 = {0.f,0.f,0.f,0.f};
        C0 = MFMA(ax0, bx, C0); C1 = MFMA(ax1, bx, C1);
        C2 = MFMA(ax2, bx, C2); C3 = MFMA(ax3, bx, C3);
        C0 = MFMA(w0_0, bh0, C0); C1 = MFMA(w1_0, bh0, C1);
        C2 = MFMA(w2_0, bh0, C2); C3 = MFMA(w3_0, bh0, C3);
        C0 = MFMA(w0_1, bh1, C0); C1 = MFMA(w1_1, bh1, C1);
        C2 = MFMA(w2_1, bh1, C2); C3 = MFMA(w3_1, bh1, C3);
        C0 = MFMA(w0_2, bh2, C0); C1 = MFMA(w1_2, bh2, C1);
        C2 = MFMA(w2_2, bh2, C2); C3 = MFMA(w3_2, bh2, C3);
        C0 = MFMA(w0_3, bh3, C0); C1 = MFMA(w1_3, bh3, C1);
        C2 = MFMA(w2_3, bh3, C2); C3 = MFMA(w3_3, bh3, C3);

        // nonlinearity: C_j regs = (i,f,g,o) of cell (d_j, batch lr)
#define CELL(J) { \
        float ci_ = sigf(C##J[0]), cf_ = sigf(C##J[1]); \
        float cg_ = tanhf_(C##J[2]), co_ = sigf(C##J[3]); \
        cs##J = cf_ * cs##J + ci_ * cg_; \
        float hv_ = co_ * tanhf_(cs##J); \
        int wb_ = ((lr << 8) + (d##J << 1)) ^ swz; \
        *(_Float16*)((char*)hw + wb_) = (_Float16)hv_; }
        CELL(0) CELL(1) CELL(2) CELL(3)
#undef CELL
        __syncthreads();
    }

    // final states: h from last-written buffer (TB even -> hbuf0), c in regs
    {
        const size_t base = ((size_t)(b0 + lr) * 2 + dir) * 2 * NH;
#define FIN(J) { \
        int rb_ = ((lr << 8) + (d##J << 1)) ^ swz; \
        float hv_ = (float)*(const _Float16*)((const char*)hbuf0 + rb_); \
        st[base + d##J] = hv_; st[base + NH + d##J] = cs##J; }
        FIN(0) FIN(1) FIN(2) FIN(3)
#undef FIN
    }
}

// named-var repetition macros (arrays get scratch-demoted: R4/R6 evidence)
#define R8(F)  F(0)F(1)F(2)F(3)F(4)F(5)F(6)F(7)
#define R36_(F) F(8)F(9)F(10)F(11)F(12)F(13)F(14)F(15)F(16)F(17)F(18)F(19)F(20)F(21)F(22)F(23)F(24)F(25)F(26)F(27)F(28)F(29)F(30)F(31)F(32)F(33)F(34)F(35)
#define R36(F) R8(F) R36_(F)
#define R64(F) R36(F) F(36)F(37)F(38)F(39)F(40)F(41)F(42)F(43)F(44)F(45)F(46)F(47)F(48)F(49)F(50)F(51)F(52)F(53)F(54)F(55)F(56)F(57)F(58)F(59)F(60)F(61)F(62)F(63)

#define QD(Q,i0,i1,i2,i3) { a0 = fdot2f((Q).x, w##i0, a0); a1 = fdot2f((Q).y, w##i1, a1); \
                            a2 = fdot2f((Q).z, w##i2, a2); a3 = fdot2f((Q).w, w##i3, a3); }
#define QDU(Q,i0,i1,i2,i3) { a0 = fdot2f((Q).x, u##i0, a0); a1 = fdot2f((Q).y, u##i1, a1); \
                             a2 = fdot2f((Q).z, u##i2, a2); a3 = fdot2f((Q).w, u##i3, a3); }

// ---------------- decoder (R7 structure + fast sig/tanh) ----------------
__global__ __launch_bounds__(1024, 1)
void dec_kernel(const float* __restrict__ x,
                const float* __restrict__ Wih_f, const float* __restrict__ Whh_f, const float* __restrict__ b_f,
                const float* __restrict__ Wih_b, const float* __restrict__ Whh_b, const float* __restrict__ b_b,
                const float* __restrict__ Wlin, const float* __restrict__ blin,
                const float* __restrict__ st, float* __restrict__ out)
{
    __shared__ unsigned int hFh[NH / 2], hBh[NH / 2];
    __shared__ unsigned int inpH[NI / 2];
    __shared__ float g[1024];
    __shared__ float prt[NG];

    const int b    = blockIdx.x;
    const int t    = threadIdx.x;
    const int cell = t >> 9;
    const int r    = t & 511;

    const float* Wih = cell ? Wih_b : Wih_f;
    const float* Whh = cell ? Whh_b : Whh_f;
    const float* bv  = cell ? b_b   : b_f;

#define DW(K) unsigned int w##K;
    R64(DW)
#undef DW
#define DU(K) unsigned int u##K;
    R8(DU)
#undef DU
    {
        const float* xr = Wih + r * NI;
        const float* hr = Whh + r * NH;
#define LU(K) u##K = packf16(xr[2*(K)], xr[2*(K)+1]);
        R8(LU)
#undef LU
#define LH(K) w##K = packf16(hr[2*(K)], hr[2*(K)+1]);
        R64(LH)
#undef LH
    }
    const float bias = bv[r];

    float cc = 0.0f;
    if (t < 64) {
        const float* sh = st + ((b * 2 + 0) * 2 + 0) * NH;
        hFh[t] = packf16(sh[2 * t], sh[2 * t + 1]);
    } else if (t < 128) {
        const float* sh = st + ((b * 2 + 1) * 2 + 0) * NH;
        hBh[t - 64] = packf16(sh[2 * (t - 64)], sh[2 * (t - 64) + 1]);
    }
    if (t < NH) cc = st[((b * 2 + 0) * 2 + 1) * NH + t];
    else if (t >= 512 && t < 512 + NH) cc = st[((b * 2 + 1) * 2 + 1) * NH + (t - 512)];
    if (t < 8) {
        float2 v = ((const float2*)(x + (size_t)b * TB * NI + (TB - 1) * NI))[t];
        inpH[t] = packf16(v.x, v.y);
    }
    __syncthreads();

    for (int s = 0; s < PRED; ++s) {
        float a0 = bias, a1 = 0.f, a2 = 0.f, a3 = 0.f;
        uint4 q;
        {
            const uint4* xv = (const uint4*)inpH;
            q = xv[0]; QDU(q, 0, 1, 2, 3)
            q = xv[1]; QDU(q, 4, 5, 6, 7)
        }
        const uint4* hv = cell ? (const uint4*)hBh : (const uint4*)hFh;
        q = hv[0];  QD(q, 0, 1, 2, 3)
        q = hv[1];  QD(q, 4, 5, 6, 7)
        q = hv[2];  QD(q, 8, 9, 10, 11)
        q = hv[3];  QD(q, 12, 13, 14, 15)
        q = hv[4];  QD(q, 16, 17, 18, 19)
        q = hv[5];  QD(q, 20, 21, 22, 23)
        q = hv[6];  QD(q, 24, 25, 26, 27)
        q = hv[7];  QD(q, 28, 29, 30, 31)
        q = hv[8];  QD(q, 32, 33, 34, 35)
        q = hv[9];  QD(q, 36, 37, 38, 39)
        q = hv[10]; QD(q, 40, 41, 42, 43)
        q = hv[11]; QD(q, 44, 45, 46, 47)
        q = hv[12]; QD(q, 48, 49, 50, 51)
        q = hv[13]; QD(q, 52, 53, 54, 55)
        q = hv[14]; QD(q, 56, 57, 58, 59)
        q = hv[15]; QD(q, 60, 61, 62, 63)
        g[t] = (a0 + a1) + (a2 + a3);
        __syncthreads();
        if ((t < NH) || (t >= 512 && t < 512 + NH)) {
            float gi = g[t], gf = g[t + NH], gg = g[t + 2 * NH], go = g[t + 3 * NH];
            cc = sigf(gf) * cc + sigf(gi) * tanhf_(gg);
            float h = sigf(go) * tanhf_(cc);
            if (t < NH) ((_Float16*)hFh)[t] = (_Float16)h;
            else        ((_Float16*)hBh)[t - 512] = (_Float16)h;
        }
        __syncthreads();
        if (t < NG) {
            const int j = t >> 5, ch = t & 31;
            const unsigned int* hsrc = (ch < 16) ? (hFh + ch * 4) : (hBh + (ch - 16) * 4);
            const float* wl = Wlin + j * (2 * NH) + ch * 8;
            float2 v0 = unpackf16(hsrc[0]);
            float2 v1 = unpackf16(hsrc[1]);
            float2 v2 = unpackf16(hsrc[2]);
            float2 v3 = unpackf16(hsrc[3]);
            prt[t] = v0.x * wl[0] + v0.y * wl[1] + v1.x * wl[2] + v1.y * wl[3]
                   + v2.x * wl[4] + v2.y * wl[5] + v3.x * wl[6] + v3.y * wl[7];
        }
        __syncthreads();
        if (t < NI) {
            float o = blin[t];
#pragma unroll
            for (int c2 = 0; c2 < 32; ++c2) o += prt[t * 32 + c2];
            out[(size_t)b * PRED * NI + s * NI + t] = o;
            ((_Float16*)inpH)[t] = (_Float16)o;
        }
        __syncthreads();
    }
}

extern "C" void kernel_launch(void* const* d_in, const int* in_sizes, int n_in,
                              void* d_out, int out_size, void* d_ws, size_t ws_size,
                              hipStream_t stream)
{
    const float* x      = (const float*)d_in[0];
    const float* eWih_f = (const float*)d_in[1];
    const float* eWhh_f = (const float*)d_in[2];
    const float* eb_f   = (const float*)d_in[3];
    const float* eWih_b = (const float*)d_in[4];
    const float* eWhh_b = (const float*)d_in[5];
    const float* eb_b   = (const float*)d_in[6];
    const float* dWih_f = (const float*)d_in[7];
    const float* dWhh_f = (const float*)d_in[8];
    const float* db_f   = (const float*)d_in[9];
    const float* dWih_b = (const float*)d_in[10];
    const float* dWhh_b = (const float*)d_in[11];
    const float* db_b   = (const float*)d_in[12];
    const float* Wlin   = (const float*)d_in[13];
    const float* blin   = (const float*)d_in[14];

    float* st = (float*)d_ws;  // 256*2*2*128 f32 encoder final states

    enc_kernel<<<32, 512, 0, stream>>>(x, eWih_f, eWhh_f, eb_f, eWih_b, eWhh_b, eb_b, st);
    dec_kernel<<<256, 1024, 0, stream>>>(x, dWih_f, dWhh_f, db_f, dWih_b, dWhh_b, db_b,
                                         Wlin, blin, st, (float*)d_out);
}